// Round 8
// baseline (393.170 us; speedup 1.0000x reference)
//
#include <hip/hip_runtime.h>

#define N_NODES 100000
#define N_EDGES 1600000
constexpr int IN_F = 128, HID_F = 64, OUT_F = 16, N_CLS = 5;

// ---- dst-bucket partition parameters ----
constexpr int NPB = 128;                        // nodes per bucket (dst >> 7)
constexpr int NBK = (N_NODES + NPB - 1) / NPB;  // 782 buckets
constexpr int BCAP = 2400;                      // per-bucket capacity
constexpr int FCH = 4096;                       // edges per fill chunk
constexpr int NCH = (N_EDGES + FCH - 1) / FCH;  // 391 chunks

typedef __attribute__((ext_vector_type(8))) short bf16x8;  // 4 VGPR A/B frag
typedef __attribute__((ext_vector_type(4))) float f32x4;   // 4 AGPR C/D frag
typedef __attribute__((ext_vector_type(2))) unsigned short u16x2;

// bf16 helpers: values are finite floats.
__device__ __forceinline__ float bf_lo(unsigned u) {
  return __uint_as_float(u << 16);
}
__device__ __forceinline__ float bf_hi(unsigned u) {
  return __uint_as_float(u & 0xffff0000u);
}
__device__ __forceinline__ unsigned f2bf(float f) {  // RNE round to bf16
  unsigned u = __float_as_uint(f);
  return (u + 0x7fffu + ((u >> 16) & 1u)) >> 16;
}
__device__ __forceinline__ void unpack8(uint4 u, float* f) {
  f[0] = bf_lo(u.x); f[1] = bf_hi(u.x);
  f[2] = bf_lo(u.y); f[3] = bf_hi(u.y);
  f[4] = bf_lo(u.z); f[5] = bf_hi(u.z);
  f[6] = bf_lo(u.w); f[7] = bf_hi(u.w);
}

// Packed max of two bf16 lanes as u16 pairs -- exact for post-ReLU (>=0)
// bf16 values (IEEE bits monotone as unsigned). Selects v_pk_max_u16.
__device__ __forceinline__ unsigned pkmax(unsigned a, unsigned b) {
  const u16x2 r = __builtin_elementwise_max(__builtin_bit_cast(u16x2, a),
                                            __builtin_bit_cast(u16x2, b));
  return __builtin_bit_cast(unsigned, r);
}
__device__ __forceinline__ uint4 pkmax4(uint4 a, uint4 b) {
  a.x = pkmax(a.x, b.x);
  a.y = pkmax(a.y, b.y);
  a.z = pkmax(a.z, b.z);
  a.w = pkmax(a.w, b.w);
  return a;
}

// ---------------------------------------------------------------------------
// node_gemm_mfma (round-3 form, measured-best): Y = act(X1@W1 (+X2@W2) + b).
// 4 waves/block, BM=64. LDS xt[64][64 bf16] chunk-XOR-swizzled; W transposed
// at stage. Frag mappings verified (m89).
// ---------------------------------------------------------------------------
template <int K1, int FOUT, bool TWO, bool X1BF, bool X2BF, bool NORM,
          bool YBF>
__global__ __launch_bounds__(256) void node_gemm_mfma(
    const void* __restrict__ X1, const void* __restrict__ X2,
    const float* __restrict__ W1, const float* __restrict__ W2,
    const float* __restrict__ B, void* __restrict__ Y, int n) {
  constexpr int KT = 64;
  constexpr int KT2 = KT / 2;
  constexpr int NT1 = K1 / KT;
  constexpr int NT = TWO ? 2 * NT1 : NT1;
  constexpr int NFT = FOUT / 16;
  constexpr int BM = 64;
  __shared__ unsigned xt[BM * KT2];
  __shared__ unsigned wt[FOUT * KT2];

  const int tid = threadIdx.x;
  const int base = blockIdx.x * BM;
  const int wave = tid >> 6, lane = tid & 63;
  const int l15 = lane & 15, l4 = lane >> 4;

  f32x4 acc[NFT];
#pragma unroll
  for (int nt = 0; nt < NFT; ++nt) {
    const float b = B[nt * 16 + l15];
    acc[nt] = {b, b, b, b};
  }

  for (int t = 0; t < NT; ++t) {
    const bool second = TWO && t >= NT1;
    const int kt0 = (t % NT1) * KT;
#pragma unroll
    for (int q = 0; q < BM * KT2 / 256; ++q) {
      const int idx = tid + q * 256;
      const int r = idx >> 5, c2 = idx & 31;
      const int node = base + r;
      unsigned pk = 0;
      if (node < n) {
        if (second) {
          if (X2BF) {
            pk = reinterpret_cast<const unsigned*>(
                X2)[(size_t)node * (K1 / 2) + kt0 / 2 + c2];
          } else {
            const float2 f2 = reinterpret_cast<const float2*>(
                X2)[(size_t)node * (K1 / 2) + kt0 / 2 + c2];
            pk = f2bf(f2.x) | (f2bf(f2.y) << 16);
          }
        } else {
          if (X1BF) {
            pk = reinterpret_cast<const unsigned*>(
                X1)[(size_t)node * (K1 / 2) + kt0 / 2 + c2];
          } else {
            const float2 f2 = reinterpret_cast<const float2*>(
                X1)[(size_t)node * (K1 / 2) + kt0 / 2 + c2];
            pk = f2bf(f2.x) | (f2bf(f2.y) << 16);
          }
        }
      }
      xt[r * KT2 + (c2 ^ ((r & 7) << 2))] = pk;
    }
    {
      const float* __restrict__ Ws = second ? W2 : W1;
#pragma unroll
      for (int q = 0; q < FOUT * KT2 / 256; ++q) {
        const int idx = tid + q * 256;
        const int c2 = idx / FOUT, f = idx % FOUT;
        const float w0 = Ws[(size_t)(kt0 + 2 * c2) * FOUT + f];
        const float w1 = Ws[(size_t)(kt0 + 2 * c2 + 1) * FOUT + f];
        wt[f * KT2 + (c2 ^ ((f & 7) << 2))] = f2bf(w0) | (f2bf(w1) << 16);
      }
    }
    __syncthreads();
#pragma unroll
    for (int ks = 0; ks < 2; ++ks) {
      const int ar = wave * 16 + l15;
      const bf16x8 af = *reinterpret_cast<const bf16x8*>(
          &xt[ar * KT2 + (((ks * 4 + l4) ^ (l15 & 7)) << 2)]);
#pragma unroll
      for (int nt = 0; nt < NFT; ++nt) {
        const int f = nt * 16 + l15;
        const bf16x8 bfr = *reinterpret_cast<const bf16x8*>(
            &wt[f * KT2 + (((ks * 4 + l4) ^ (l15 & 7)) << 2)]);
        acc[nt] =
            __builtin_amdgcn_mfma_f32_16x16x32_bf16(af, bfr, acc[nt], 0, 0, 0);
      }
    }
    __syncthreads();
  }

  if (NORM) {
    float ss[4] = {0.f, 0.f, 0.f, 0.f};
#pragma unroll
    for (int nt = 0; nt < NFT; ++nt)
#pragma unroll
      for (int r = 0; r < 4; ++r) ss[r] += acc[nt][r] * acc[nt][r];
#pragma unroll
    for (int r = 0; r < 4; ++r) {
#pragma unroll
      for (int off = 1; off < 16; off <<= 1) ss[r] += __shfl_xor(ss[r], off, 16);
      ss[r] = 1.0f / fmaxf(sqrtf(ss[r]), 1e-12f);
    }
#pragma unroll
    for (int nt = 0; nt < NFT; ++nt)
#pragma unroll
      for (int r = 0; r < 4; ++r) acc[nt][r] = fmaxf(acc[nt][r] * ss[r], 0.f);
  } else {
#pragma unroll
    for (int nt = 0; nt < NFT; ++nt)
#pragma unroll
      for (int r = 0; r < 4; ++r) acc[nt][r] = fmaxf(acc[nt][r], 0.f);
  }
#pragma unroll
  for (int r = 0; r < 4; ++r) {
    const int node = base + wave * 16 + l4 * 4 + r;
    if (node < n) {
#pragma unroll
      for (int nt = 0; nt < NFT; ++nt) {
        if (YBF)
          reinterpret_cast<unsigned short*>(Y)[(size_t)node * FOUT + nt * 16 +
                                               l15] =
              (unsigned short)f2bf(acc[nt][r]);
        else
          reinterpret_cast<float*>(Y)[(size_t)node * FOUT + nt * 16 + l15] =
              acc[nt][r];
      }
    }
  }
}

// ---------------------------------------------------------------------------
// bucket_fill: single-pass radix partition of edges into NBK dst-buckets
// (round-3 form, FCH=4096).
// ---------------------------------------------------------------------------
__global__ __launch_bounds__(256) void bucket_fill(
    const int* __restrict__ src, const int* __restrict__ dst,
    int* __restrict__ cursor, unsigned* __restrict__ bedges) {
  __shared__ int hist[NBK];
  __shared__ int bbase[NBK];
  const int tid = threadIdx.x;
  const int c0 = blockIdx.x * FCH;
  const int n4 = (min(FCH, N_EDGES - c0)) >> 2;
  for (int i = tid; i < NBK; i += 256) hist[i] = 0;
  __syncthreads();
  const int4* __restrict__ s4 = reinterpret_cast<const int4*>(src + c0);
  const int4* __restrict__ d4 = reinterpret_cast<const int4*>(dst + c0);
  int4 sv[4], dv[4];
#pragma unroll
  for (int q = 0; q < 4; ++q) {
    const int i = tid + q * 256;
    if (i < n4) {
      sv[q] = s4[i];
      dv[q] = d4[i];
      atomicAdd(&hist[dv[q].x >> 7], 1);
      atomicAdd(&hist[dv[q].y >> 7], 1);
      atomicAdd(&hist[dv[q].z >> 7], 1);
      atomicAdd(&hist[dv[q].w >> 7], 1);
    }
  }
  __syncthreads();
  for (int i = tid; i < NBK; i += 256) {
    const int c = hist[i];
    bbase[i] = c ? atomicAdd(&cursor[i], c) : 0;
    hist[i] = 0;  // reuse as rank counter
  }
  __syncthreads();
#pragma unroll
  for (int q = 0; q < 4; ++q) {
    const int i = tid + q * 256;
    if (i < n4) {
#define PUT(dd, ss)                                        \
  {                                                        \
    const int b_ = (dd) >> 7;                              \
    const int r_ = bbase[b_] + atomicAdd(&hist[b_], 1);    \
    if (r_ < BCAP)                                         \
      bedges[(size_t)b_ * BCAP + r_] =                     \
          (unsigned)(ss) | ((unsigned)((dd) & 127) << 20); \
  }
      PUT(dv[q].x, sv[q].x)
      PUT(dv[q].y, sv[q].y)
      PUT(dv[q].z, sv[q].z)
      PUT(dv[q].w, sv[q].w)
#undef PUT
    }
  }
}

// ---------------------------------------------------------------------------
// bucket_sort: one block per bucket. LDS counting-sort by dst_local.
// Emits ninfo[node] = beg_local | (count << 12).
// ---------------------------------------------------------------------------
__global__ __launch_bounds__(256) void bucket_sort(unsigned* __restrict__ bedges,
                                                   const int* __restrict__ cnt,
                                                   int* __restrict__ ninfo) {
  __shared__ unsigned el[BCAP];
  __shared__ unsigned el2[BCAP];
  __shared__ int hist[NPB];
  __shared__ int csum[NPB];
  __shared__ int posl[NPB];
  const int b = blockIdx.x;
  const int n = min(cnt[b], BCAP);
  unsigned* __restrict__ bp = bedges + (size_t)b * BCAP;
  for (int i = threadIdx.x; i < n; i += 256) el[i] = bp[i];
  for (int i = threadIdx.x; i < NPB; i += 256) hist[i] = 0;
  __syncthreads();
  for (int i = threadIdx.x; i < n; i += 256) atomicAdd(&hist[el[i] >> 20], 1);
  __syncthreads();
  if (threadIdx.x < NPB) csum[threadIdx.x] = hist[threadIdx.x];
  __syncthreads();
  for (int off = 1; off < NPB; off <<= 1) {
    int u = 0;
    if (threadIdx.x < NPB && threadIdx.x >= off) u = csum[threadIdx.x - off];
    __syncthreads();
    if (threadIdx.x < NPB) csum[threadIdx.x] += u;
    __syncthreads();
  }
  if (threadIdx.x < NPB) {
    const int c = hist[threadIdx.x];
    const int beg = csum[threadIdx.x] - c;  // exclusive prefix
    posl[threadIdx.x] = beg;
    const int node = b * NPB + threadIdx.x;
    if (node < N_NODES) ninfo[node] = beg | (c << 12);
  }
  __syncthreads();
  for (int i = threadIdx.x; i < n; i += 256) {
    const unsigned w = el[i];
    const int p = atomicAdd(&posl[w >> 20], 1);
    el2[p] = w & 0xFFFFF;
  }
  __syncthreads();
  for (int i = threadIdx.x; i < n; i += 256) bp[i] = el2[i];
}

// ---------------------------------------------------------------------------
// gather_max_pk<LPN>: per-node segment-max over sorted bucket runs.
// DUAL-STREAM form: rounds 2/3 both compiled to VGPR=20 (the UNR-deep batch
// was silently serialized -- 6 uint4 in flight needs >=24 VGPRs), so the
// "deeper pipeline" experiment never ran. Here each lane-group owns TWO
// independent node streams with separate accumulators/cursors; all 8 row
// loads (4+4) are issued before any fold, and the streams are register-
// disjoint, guaranteeing >=2x outstanding misses regardless of in-stream
// scheduling. Predicated select-to-0 folds are identity (values >= 0) so
// degree mismatch needs no divergent loop; empty segments stay 0 ==
// reference's where(isneginf, 0).
// ---------------------------------------------------------------------------
template <int LPN>
__global__ __launch_bounds__(256, 8) void gather_max_pk(
    const uint4* __restrict__ M4, const int* __restrict__ ninfo,
    const int* __restrict__ sedges, uint4* __restrict__ A4) {
  constexpr int GPB = 256 / LPN;
  constexpr int UNR = 4;  // per-stream batch depth (8 loads in flight total)
  const int li = threadIdx.x % LPN;
  const int g = blockIdx.x * GPB + threadIdx.x / LPN;
  const int gstride = gridDim.x * GPB;
  const uint4 z = {0u, 0u, 0u, 0u};
  for (int n0 = g * 2; n0 < N_NODES; n0 += 2 * gstride) {
    const int n1 = n0 + 1;
    const int w0 = ninfo[n0];
    const int w1 = (n1 < N_NODES) ? ninfo[n1] : 0;
    const int c0 = w0 >> 12, c1 = w1 >> 12;
    const int b0 = (n0 >> 7) * BCAP + (w0 & 0xFFF);
    const int b1 = (n1 >> 7) * BCAP + (w1 & 0xFFF);
    const int e0 = b0 + c0 - 1, e1 = b1 + c1 - 1;  // last valid (if cnt>0)
    const int r0 = (c0 + UNR - 1) / UNR, r1 = (c1 + UNR - 1) / UNR;
    const int rounds = max(r0, r1);
    uint4 a0 = z, a1 = z;
    for (int t = 0; t < rounds; ++t) {
      const bool p0 = t < r0, p1 = t < r1;
      const int j0 = b0 + t * UNR, j1 = b1 + t * UNR;
      int s0[UNR], s1[UNR];
#pragma unroll
      for (int q = 0; q < UNR; ++q) {
        s0[q] = p0 ? sedges[min(j0 + q, e0)] : 0;
        s1[q] = p1 ? sedges[min(j1 + q, e1)] : 0;
      }
      uint4 u0[UNR], u1[UNR];
#pragma unroll
      for (int q = 0; q < UNR; ++q) u0[q] = p0 ? M4[(size_t)s0[q] * LPN + li] : z;
#pragma unroll
      for (int q = 0; q < UNR; ++q) u1[q] = p1 ? M4[(size_t)s1[q] * LPN + li] : z;
#pragma unroll
      for (int q = 0; q < UNR; ++q) {
        a0 = pkmax4(a0, u0[q]);
        a1 = pkmax4(a1, u1[q]);
      }
    }
    A4[(size_t)n0 * LPN + li] = a0;
    if (n1 < N_NODES) A4[(size_t)n1 * LPN + li] = a1;
  }
}

// ---------------------------------------------------------------------------
// Edge scoring (round-3 form), bf16 h rows (16 bf16 = 2x uint4 per row).
// Stores are wave-contiguous (thread e covers OUT[5e..5e+5)).
// ---------------------------------------------------------------------------
__global__ __launch_bounds__(256) void edge_score_bf16_kernel(
    const uint4* __restrict__ H, const int* __restrict__ src,
    const int* __restrict__ dst, const float* __restrict__ PW,
    const float* __restrict__ PB, float* __restrict__ OUT) {
  __shared__ float Wl[2 * OUT_F * N_CLS];
  __shared__ float bl[N_CLS];
  if (threadIdx.x < 2 * OUT_F * N_CLS) Wl[threadIdx.x] = PW[threadIdx.x];
  if (threadIdx.x < N_CLS) bl[threadIdx.x] = PB[threadIdx.x];
  __syncthreads();
  for (int e = blockIdx.x * 256 + threadIdx.x; e < N_EDGES;
       e += gridDim.x * 256) {
    const int s = src[e], d = dst[e];
    const uint4 s0 = H[(size_t)s * 2], s1 = H[(size_t)s * 2 + 1];
    const uint4 d0 = H[(size_t)d * 2], d1 = H[(size_t)d * 2 + 1];
    float hs[OUT_F], hd[OUT_F];
    unpack8(s0, hs); unpack8(s1, hs + 8);
    unpack8(d0, hd); unpack8(d1, hd + 8);
    float acc[N_CLS];
#pragma unroll
    for (int c = 0; c < N_CLS; ++c) acc[c] = bl[c];
#pragma unroll
    for (int k = 0; k < OUT_F; ++k) {
#pragma unroll
      for (int c = 0; c < N_CLS; ++c) {
        acc[c] = fmaf(hs[k], Wl[k * N_CLS + c], acc[c]);
        acc[c] = fmaf(hd[k], Wl[(OUT_F + k) * N_CLS + c], acc[c]);
      }
    }
    float* o = OUT + (size_t)e * N_CLS;
#pragma unroll
    for (int c = 0; c < N_CLS; ++c) o[c] = acc[c];
  }
}

extern "C" void kernel_launch(void* const* d_in, const int* in_sizes, int n_in,
                              void* d_out, int out_size, void* d_ws,
                              size_t ws_size, hipStream_t stream) {
  const float* x = (const float*)d_in[0];
  const int* src = (const int*)d_in[1];
  const int* dst = (const int*)d_in[2];
  const float* pool1_W = (const float*)d_in[3];
  const float* pool1_b = (const float*)d_in[4];
  const float* self1_W = (const float*)d_in[5];
  const float* neigh1_W = (const float*)d_in[6];
  const float* bias1 = (const float*)d_in[7];
  const float* pool2_W = (const float*)d_in[8];
  const float* pool2_b = (const float*)d_in[9];
  const float* self2_W = (const float*)d_in[10];
  const float* neigh2_W = (const float*)d_in[11];
  const float* bias2 = (const float*)d_in[12];
  const float* pred_W = (const float*)d_in[13];
  const float* pred_b = (const float*)d_in[14];
  float* out = (float*)d_out;

  // Workspace (~59.1MB): cursor + ninfo + bedges (~7.92MB) + bufA + bufB.
  int* cursor = (int*)d_ws;                        // 1024 (uses NBK=782)
  int* ninfo = cursor + 1024;                      // 100352 (uses 100000)
  unsigned* bedges = (unsigned*)(ninfo + 100352);  // 782*2400 = 1,876,800
  char* bufA = (char*)(bedges + (size_t)NBK * BCAP);  // 25.6MB
  char* bufB = bufA + 25600000;                       // 25.6MB
  void* m1 = (void*)bufA;                 // bf16 [N][128] (25.6MB)
  void* agg1 = (void*)bufB;               // bf16 [N][128]
  void* h1 = (void*)bufA;                 // bf16 [N][64] 12.8MB (m1 dead)
  void* m2 = (void*)bufB;                 // bf16 [N][64] (agg1 dead)
  void* agg2 = (void*)(bufA + 12800000);  // bf16 [N][64] (m1 upper half dead)
  void* h2 = (void*)bufB;                 // bf16 [N][16] (m2 dead after gather2)

  // ---- edge bucketing + bucket-local counting sort ----
  hipMemsetAsync(cursor, 0, 1024 * sizeof(int), stream);
  bucket_fill<<<NCH, 256, 0, stream>>>(src, dst, cursor, bedges);
  bucket_sort<<<NBK, 256, 0, stream>>>(bedges, cursor, ninfo);

  const int ngrid = (N_NODES + 63) / 64;  // 1563

  // ---- Layer 1 ----
  node_gemm_mfma<IN_F, IN_F, false, false, false, false, true>
      <<<ngrid, 256, 0, stream>>>(x, nullptr, pool1_W, nullptr, pool1_b, m1,
                                  N_NODES);
  gather_max_pk<16><<<2048, 256, 0, stream>>>(
      (const uint4*)m1, ninfo, (const int*)bedges, (uint4*)agg1);
  node_gemm_mfma<IN_F, HID_F, true, false, true, true, true>
      <<<ngrid, 256, 0, stream>>>(x, agg1, self1_W, neigh1_W, bias1, h1,
                                  N_NODES);

  // ---- Layer 2 ----
  node_gemm_mfma<HID_F, HID_F, false, true, false, false, true>
      <<<ngrid, 256, 0, stream>>>(h1, nullptr, pool2_W, nullptr, pool2_b, m2,
                                  N_NODES);
  gather_max_pk<8><<<2048, 256, 0, stream>>>(
      (const uint4*)m2, ninfo, (const int*)bedges, (uint4*)agg2);
  node_gemm_mfma<HID_F, OUT_F, true, true, true, true, true>
      <<<ngrid, 256, 0, stream>>>(h1, agg2, self2_W, neigh2_W, bias2, h2,
                                  N_NODES);

  // ---- Edge scoring ----
  edge_score_bf16_kernel<<<4096, 256, 0, stream>>>((const uint4*)h2, src, dst,
                                                   pred_W, pred_b, out);
}

// Round 9
// 238.125 us; speedup vs baseline: 1.6511x; 1.6511x over previous
//
#include <hip/hip_runtime.h>

#define N_NODES 100000
#define N_EDGES 1600000
constexpr int IN_F = 128, HID_F = 64, OUT_F = 16, N_CLS = 5;

// ---- dst-bucket partition parameters ----
constexpr int NPB = 128;                        // nodes per bucket (dst >> 7)
constexpr int NBK = (N_NODES + NPB - 1) / NPB;  // 782 buckets
constexpr int BCAP = 2400;                      // per-bucket capacity (mean 2048 + 7.8 sigma)
constexpr int FCH = 4096;                       // edges per fill chunk
constexpr int NCH = (N_EDGES + FCH - 1) / FCH;  // 391 chunks

typedef __attribute__((ext_vector_type(8))) short bf16x8;  // 4 VGPR A/B frag
typedef __attribute__((ext_vector_type(4))) float f32x4;   // 4 AGPR C/D frag
typedef __attribute__((ext_vector_type(2))) unsigned short u16x2;

// bf16 helpers: values are finite floats.
__device__ __forceinline__ float bf_lo(unsigned u) {
  return __uint_as_float(u << 16);
}
__device__ __forceinline__ float bf_hi(unsigned u) {
  return __uint_as_float(u & 0xffff0000u);
}
__device__ __forceinline__ unsigned f2bf(float f) {  // RNE round to bf16
  unsigned u = __float_as_uint(f);
  return (u + 0x7fffu + ((u >> 16) & 1u)) >> 16;
}
__device__ __forceinline__ void unpack8(uint4 u, float* f) {
  f[0] = bf_lo(u.x); f[1] = bf_hi(u.x);
  f[2] = bf_lo(u.y); f[3] = bf_hi(u.y);
  f[4] = bf_lo(u.z); f[5] = bf_hi(u.z);
  f[6] = bf_lo(u.w); f[7] = bf_hi(u.w);
}

// Packed max of two bf16 lanes as u16 pairs -- exact for post-ReLU (>=0)
// bf16 values since IEEE bits are monotone as unsigned there. Selects
// v_pk_max_u16 (single VALU op), no unpack/repack needed.
__device__ __forceinline__ unsigned pkmax(unsigned a, unsigned b) {
  const u16x2 r = __builtin_elementwise_max(__builtin_bit_cast(u16x2, a),
                                            __builtin_bit_cast(u16x2, b));
  return __builtin_bit_cast(unsigned, r);
}
__device__ __forceinline__ uint4 pkmax4(uint4 a, uint4 b) {
  a.x = pkmax(a.x, b.x);
  a.y = pkmax(a.y, b.y);
  a.z = pkmax(a.z, b.z);
  a.w = pkmax(a.w, b.w);
  return a;
}

// ---------------------------------------------------------------------------
// node_gemm_mfma: Y[n] = act( X1[n] @ W1 (+ X2[n] @ W2) + b ), bf16 MFMA.
// 4 waves/block, BM=64 (16 node-rows per wave). K tiled in KT=64 bf16.
// LDS: xt[64 rows][64 bf16] (128B rows, chunk XOR-swizzle c^=(row&7)) and
// wt[FOUT][64 bf16] (W transposed at stage so B-frags are 16B contiguous).
// Frags: A row=lane&15, k=(lane>>4)*8+j; B col=lane&15, same k.
// C/D: col=lane&15, row=(lane>>4)*4+reg [verified m89 mapping].
// ---------------------------------------------------------------------------
template <int K1, int FOUT, bool TWO, bool X1BF, bool X2BF, bool NORM,
          bool YBF>
__global__ __launch_bounds__(256) void node_gemm_mfma(
    const void* __restrict__ X1, const void* __restrict__ X2,
    const float* __restrict__ W1, const float* __restrict__ W2,
    const float* __restrict__ B, void* __restrict__ Y, int n) {
  constexpr int KT = 64;         // K-tile in bf16 elements
  constexpr int KT2 = KT / 2;    // 32 u32 per LDS row (128B, bank-aligned)
  constexpr int NT1 = K1 / KT;
  constexpr int NT = TWO ? 2 * NT1 : NT1;
  constexpr int NFT = FOUT / 16;  // n-tiles per wave
  constexpr int BM = 64;
  __shared__ unsigned xt[BM * KT2];
  __shared__ unsigned wt[FOUT * KT2];

  const int tid = threadIdx.x;
  const int base = blockIdx.x * BM;
  const int wave = tid >> 6, lane = tid & 63;
  const int l15 = lane & 15, l4 = lane >> 4;

  f32x4 acc[NFT];
#pragma unroll
  for (int nt = 0; nt < NFT; ++nt) {
    const float b = B[nt * 16 + l15];
    acc[nt] = {b, b, b, b};
  }

  for (int t = 0; t < NT; ++t) {
    const bool second = TWO && t >= NT1;
    const int kt0 = (t % NT1) * KT;
    // ---- stage X tile (packed bf16 u32, swizzled) ----
#pragma unroll
    for (int q = 0; q < BM * KT2 / 256; ++q) {
      const int idx = tid + q * 256;
      const int r = idx >> 5, c2 = idx & 31;
      const int node = base + r;
      unsigned pk = 0;
      if (node < n) {
        if (second) {
          if (X2BF) {
            pk = reinterpret_cast<const unsigned*>(
                X2)[(size_t)node * (K1 / 2) + kt0 / 2 + c2];
          } else {
            const float2 f2 = reinterpret_cast<const float2*>(
                X2)[(size_t)node * (K1 / 2) + kt0 / 2 + c2];
            pk = f2bf(f2.x) | (f2bf(f2.y) << 16);
          }
        } else {
          if (X1BF) {
            pk = reinterpret_cast<const unsigned*>(
                X1)[(size_t)node * (K1 / 2) + kt0 / 2 + c2];
          } else {
            const float2 f2 = reinterpret_cast<const float2*>(
                X1)[(size_t)node * (K1 / 2) + kt0 / 2 + c2];
            pk = f2bf(f2.x) | (f2bf(f2.y) << 16);
          }
        }
      }
      xt[r * KT2 + (c2 ^ ((r & 7) << 2))] = pk;
    }
    // ---- stage W tile transposed: wt[f][k] = W[kt0+k][f] ----
    {
      const float* __restrict__ Ws = second ? W2 : W1;
#pragma unroll
      for (int q = 0; q < FOUT * KT2 / 256; ++q) {
        const int idx = tid + q * 256;
        const int c2 = idx / FOUT, f = idx % FOUT;
        const float w0 = Ws[(size_t)(kt0 + 2 * c2) * FOUT + f];
        const float w1 = Ws[(size_t)(kt0 + 2 * c2 + 1) * FOUT + f];
        wt[f * KT2 + (c2 ^ ((f & 7) << 2))] = f2bf(w0) | (f2bf(w1) << 16);
      }
    }
    __syncthreads();
    // ---- MFMA: 2 k-steps of K=32 ----
#pragma unroll
    for (int ks = 0; ks < 2; ++ks) {
      const int ar = wave * 16 + l15;
      const bf16x8 af = *reinterpret_cast<const bf16x8*>(
          &xt[ar * KT2 + (((ks * 4 + l4) ^ (l15 & 7)) << 2)]);
#pragma unroll
      for (int nt = 0; nt < NFT; ++nt) {
        const int f = nt * 16 + l15;
        const bf16x8 bfr = *reinterpret_cast<const bf16x8*>(
            &wt[f * KT2 + (((ks * 4 + l4) ^ (l15 & 7)) << 2)]);
        acc[nt] =
            __builtin_amdgcn_mfma_f32_16x16x32_bf16(af, bfr, acc[nt], 0, 0, 0);
      }
    }
    __syncthreads();
  }

  // ---- epilogue: lane holds D[l4*4+reg][nt*16+l15] ----
  if (NORM) {
    float ss[4] = {0.f, 0.f, 0.f, 0.f};
#pragma unroll
    for (int nt = 0; nt < NFT; ++nt)
#pragma unroll
      for (int r = 0; r < 4; ++r) ss[r] += acc[nt][r] * acc[nt][r];
#pragma unroll
    for (int r = 0; r < 4; ++r) {
#pragma unroll
      for (int off = 1; off < 16; off <<= 1) ss[r] += __shfl_xor(ss[r], off, 16);
      ss[r] = 1.0f / fmaxf(sqrtf(ss[r]), 1e-12f);
    }
#pragma unroll
    for (int nt = 0; nt < NFT; ++nt)
#pragma unroll
      for (int r = 0; r < 4; ++r) acc[nt][r] = fmaxf(acc[nt][r] * ss[r], 0.f);
  } else {
#pragma unroll
    for (int nt = 0; nt < NFT; ++nt)
#pragma unroll
      for (int r = 0; r < 4; ++r) acc[nt][r] = fmaxf(acc[nt][r], 0.f);
  }
#pragma unroll
  for (int r = 0; r < 4; ++r) {
    const int node = base + wave * 16 + l4 * 4 + r;
    if (node < n) {
#pragma unroll
      for (int nt = 0; nt < NFT; ++nt) {
        if (YBF)
          reinterpret_cast<unsigned short*>(Y)[(size_t)node * FOUT + nt * 16 +
                                               l15] =
              (unsigned short)f2bf(acc[nt][r]);
        else
          reinterpret_cast<float*>(Y)[(size_t)node * FOUT + nt * 16 + l15] =
              acc[nt][r];
      }
    }
  }
}

// ---------------------------------------------------------------------------
// bucket_fill: single-pass radix partition of edges into NBK dst-buckets.
// Capacity layout (bucket b owns bedges[b*BCAP .. b*BCAP+BCAP)) removes the
// global scan. Per 4096-edge chunk: LDS histogram -> ONE cursor atomicAdd per
// nonzero bucket -> rank via LDS atomicAdd -> clustered line-local writes.
// Packed word: src (20 bits) | dst_local (7 bits) << 20.
// ---------------------------------------------------------------------------
__global__ __launch_bounds__(256) void bucket_fill(
    const int* __restrict__ src, const int* __restrict__ dst,
    int* __restrict__ cursor, unsigned* __restrict__ bedges) {
  __shared__ int hist[NBK];
  __shared__ int bbase[NBK];
  const int tid = threadIdx.x;
  const int c0 = blockIdx.x * FCH;
  const int n4 = (min(FCH, N_EDGES - c0)) >> 2;  // int4 count in this chunk
  for (int i = tid; i < NBK; i += 256) hist[i] = 0;
  __syncthreads();
  const int4* __restrict__ s4 = reinterpret_cast<const int4*>(src + c0);
  const int4* __restrict__ d4 = reinterpret_cast<const int4*>(dst + c0);
  int4 sv[4], dv[4];
#pragma unroll
  for (int q = 0; q < 4; ++q) {
    const int i = tid + q * 256;
    if (i < n4) {
      sv[q] = s4[i];
      dv[q] = d4[i];
      atomicAdd(&hist[dv[q].x >> 7], 1);
      atomicAdd(&hist[dv[q].y >> 7], 1);
      atomicAdd(&hist[dv[q].z >> 7], 1);
      atomicAdd(&hist[dv[q].w >> 7], 1);
    }
  }
  __syncthreads();
  for (int i = tid; i < NBK; i += 256) {
    const int c = hist[i];
    bbase[i] = c ? atomicAdd(&cursor[i], c) : 0;
    hist[i] = 0;  // reuse as rank counter
  }
  __syncthreads();
#pragma unroll
  for (int q = 0; q < 4; ++q) {
    const int i = tid + q * 256;
    if (i < n4) {
#define PUT(dd, ss)                                        \
  {                                                        \
    const int b_ = (dd) >> 7;                              \
    const int r_ = bbase[b_] + atomicAdd(&hist[b_], 1);    \
    if (r_ < BCAP)                                         \
      bedges[(size_t)b_ * BCAP + r_] =                     \
          (unsigned)(ss) | ((unsigned)((dd) & 127) << 20); \
  }
      PUT(dv[q].x, sv[q].x)
      PUT(dv[q].y, sv[q].y)
      PUT(dv[q].z, sv[q].z)
      PUT(dv[q].w, sv[q].w)
#undef PUT
    }
  }
}

// ---------------------------------------------------------------------------
// bucket_sort: one block per bucket. Counting-sort the bucket's edges by
// dst_local entirely in LDS (histogram -> Hillis-Steele scan -> rank
// scatter -> coalesced write-back in place, now storing plain src ids).
// Emits ninfo[node] = beg_local | (count << 12) (both < 4096). This gives
// the gather a per-node contiguous run with zero global scan.
// ---------------------------------------------------------------------------
__global__ __launch_bounds__(256) void bucket_sort(unsigned* __restrict__ bedges,
                                                   const int* __restrict__ cnt,
                                                   int* __restrict__ ninfo) {
  __shared__ unsigned el[BCAP];
  __shared__ unsigned el2[BCAP];
  __shared__ int hist[NPB];
  __shared__ int csum[NPB];
  __shared__ int posl[NPB];
  const int b = blockIdx.x;
  const int n = min(cnt[b], BCAP);
  unsigned* __restrict__ bp = bedges + (size_t)b * BCAP;
  for (int i = threadIdx.x; i < n; i += 256) el[i] = bp[i];
  for (int i = threadIdx.x; i < NPB; i += 256) hist[i] = 0;
  __syncthreads();
  for (int i = threadIdx.x; i < n; i += 256) atomicAdd(&hist[el[i] >> 20], 1);
  __syncthreads();
  if (threadIdx.x < NPB) csum[threadIdx.x] = hist[threadIdx.x];
  __syncthreads();
  for (int off = 1; off < NPB; off <<= 1) {
    int u = 0;
    if (threadIdx.x < NPB && threadIdx.x >= off) u = csum[threadIdx.x - off];
    __syncthreads();
    if (threadIdx.x < NPB) csum[threadIdx.x] += u;
    __syncthreads();
  }
  if (threadIdx.x < NPB) {
    const int c = hist[threadIdx.x];
    const int beg = csum[threadIdx.x] - c;  // exclusive prefix
    posl[threadIdx.x] = beg;
    const int node = b * NPB + threadIdx.x;
    if (node < N_NODES) ninfo[node] = beg | (c << 12);
  }
  __syncthreads();
  for (int i = threadIdx.x; i < n; i += 256) {
    const unsigned w = el[i];
    const int p = atomicAdd(&posl[w >> 20], 1);
    el2[p] = w & 0xFFFFF;
  }
  __syncthreads();
  for (int i = threadIdx.x; i < n; i += 256) bp[i] = el2[i];
}

// ---------------------------------------------------------------------------
// gather_max_pk<LPN>: per-node segment-max over sorted bucket runs.
// LPN lanes per node, uint4 = 8 bf16/lane. No LDS, no atomics; packed
// v_pk_max_u16 folds (exact for post-ReLU bf16). Zero-init == reference's
// where(isneginf, 0) for empty segments. Idempotent-clamped batches (no
// tail loop). At the scattered-line-throughput ceiling: three structurally
// different MLP-deepening attempts (r3 UNR=6, r8 dual-stream, r2 4-deep)
// all compiled to the same serialized load->fold chain (VGPR 20-24) with
// identical-or-worse time at identical FETCH (dedup floor). Do not touch.
// ---------------------------------------------------------------------------
template <int LPN>
__global__ __launch_bounds__(256, 8) void gather_max_pk(
    const uint4* __restrict__ M4, const int* __restrict__ ninfo,
    const int* __restrict__ sedges, uint4* __restrict__ A4) {
  constexpr int GPB = 256 / LPN;
  constexpr int UNR = 6;
  const int li = threadIdx.x % LPN;
  const int g0 = blockIdx.x * GPB + threadIdx.x / LPN;
  const int stride = gridDim.x * GPB;
  for (int node = g0; node < N_NODES; node += stride) {
    const int w = ninfo[node];
    const int cnt = w >> 12;
    uint4 a = {0u, 0u, 0u, 0u};
    if (cnt) {
      const int beg = (node >> 7) * BCAP + (w & 0xFFF);
      const int last = beg + cnt - 1;
      for (int j = beg; j <= last; j += UNR) {
        int s[UNR];
#pragma unroll
        for (int q = 0; q < UNR; ++q) s[q] = sedges[min(j + q, last)];
        uint4 u[UNR];
#pragma unroll
        for (int q = 0; q < UNR; ++q) u[q] = M4[(size_t)s[q] * LPN + li];
#pragma unroll
        for (int q = 0; q < UNR; ++q) a = pkmax4(a, u[q]);
      }
    }
    A4[(size_t)node * LPN + li] = a;
  }
}

// ---------------------------------------------------------------------------
// Edge scoring, bf16 h rows (16 bf16 = 2x uint4 per row).
// Stores are wave-contiguous (thread e covers OUT[5e..5e+5)).
// ---------------------------------------------------------------------------
__global__ __launch_bounds__(256) void edge_score_bf16_kernel(
    const uint4* __restrict__ H, const int* __restrict__ src,
    const int* __restrict__ dst, const float* __restrict__ PW,
    const float* __restrict__ PB, float* __restrict__ OUT) {
  __shared__ float Wl[2 * OUT_F * N_CLS];
  __shared__ float bl[N_CLS];
  if (threadIdx.x < 2 * OUT_F * N_CLS) Wl[threadIdx.x] = PW[threadIdx.x];
  if (threadIdx.x < N_CLS) bl[threadIdx.x] = PB[threadIdx.x];
  __syncthreads();
  for (int e = blockIdx.x * 256 + threadIdx.x; e < N_EDGES;
       e += gridDim.x * 256) {
    const int s = src[e], d = dst[e];
    const uint4 s0 = H[(size_t)s * 2], s1 = H[(size_t)s * 2 + 1];
    const uint4 d0 = H[(size_t)d * 2], d1 = H[(size_t)d * 2 + 1];
    float hs[OUT_F], hd[OUT_F];
    unpack8(s0, hs); unpack8(s1, hs + 8);
    unpack8(d0, hd); unpack8(d1, hd + 8);
    float acc[N_CLS];
#pragma unroll
    for (int c = 0; c < N_CLS; ++c) acc[c] = bl[c];
#pragma unroll
    for (int k = 0; k < OUT_F; ++k) {
#pragma unroll
      for (int c = 0; c < N_CLS; ++c) {
        acc[c] = fmaf(hs[k], Wl[k * N_CLS + c], acc[c]);
        acc[c] = fmaf(hd[k], Wl[(OUT_F + k) * N_CLS + c], acc[c]);
      }
    }
    float* o = OUT + (size_t)e * N_CLS;
#pragma unroll
    for (int c = 0; c < N_CLS; ++c) o[c] = acc[c];
  }
}

extern "C" void kernel_launch(void* const* d_in, const int* in_sizes, int n_in,
                              void* d_out, int out_size, void* d_ws,
                              size_t ws_size, hipStream_t stream) {
  const float* x = (const float*)d_in[0];
  const int* src = (const int*)d_in[1];
  const int* dst = (const int*)d_in[2];
  const float* pool1_W = (const float*)d_in[3];
  const float* pool1_b = (const float*)d_in[4];
  const float* self1_W = (const float*)d_in[5];
  const float* neigh1_W = (const float*)d_in[6];
  const float* bias1 = (const float*)d_in[7];
  const float* pool2_W = (const float*)d_in[8];
  const float* pool2_b = (const float*)d_in[9];
  const float* self2_W = (const float*)d_in[10];
  const float* neigh2_W = (const float*)d_in[11];
  const float* bias2 = (const float*)d_in[12];
  const float* pred_W = (const float*)d_in[13];
  const float* pred_b = (const float*)d_in[14];
  float* out = (float*)d_out;

  // Workspace: cursor (1024) + ninfo (100352) + bedges (NBK*BCAP ~7.5MB)
  // + two 25.6MB bf16 regions. ~59.1MB total.
  int* cursor = (int*)d_ws;                      // 1024 (uses NBK=782)
  int* ninfo = cursor + 1024;                    // 100352 (uses 100000)
  unsigned* bedges = (unsigned*)(ninfo + 100352);  // 782*2400 = 1,876,800
  char* bufA = (char*)(bedges + (size_t)NBK * BCAP);  // 25.6MB
  char* bufB = bufA + 25600000;                       // 25.6MB
  void* m1 = (void*)bufA;                 // bf16 [N][128] (25.6MB)
  void* agg1 = (void*)bufB;               // bf16 [N][128]
  void* h1 = (void*)bufA;                 // bf16 [N][64] 12.8MB (m1 dead)
  void* m2 = (void*)bufB;                 // bf16 [N][64] (agg1 dead)
  void* agg2 = (void*)(bufA + 12800000);  // bf16 [N][64] (m1 upper half, dead)
  void* h2 = (void*)bufB;                 // bf16 [N][16] (m2 dead after gather2)

  // ---- edge bucketing + bucket-local counting sort ----
  hipMemsetAsync(cursor, 0, 1024 * sizeof(int), stream);
  bucket_fill<<<NCH, 256, 0, stream>>>(src, dst, cursor, bedges);
  bucket_sort<<<NBK, 256, 0, stream>>>(bedges, cursor, ninfo);

  const int ngrid = (N_NODES + 63) / 64;  // 1563

  // ---- Layer 1 ----
  node_gemm_mfma<IN_F, IN_F, false, false, false, false, true>
      <<<ngrid, 256, 0, stream>>>(x, nullptr, pool1_W, nullptr, pool1_b, m1,
                                  N_NODES);
  gather_max_pk<16><<<2048, 256, 0, stream>>>(
      (const uint4*)m1, ninfo, (const int*)bedges, (uint4*)agg1);
  node_gemm_mfma<IN_F, HID_F, true, false, true, true, true>
      <<<ngrid, 256, 0, stream>>>(x, agg1, self1_W, neigh1_W, bias1, h1,
                                  N_NODES);

  // ---- Layer 2 ----
  node_gemm_mfma<HID_F, HID_F, false, true, false, false, true>
      <<<ngrid, 256, 0, stream>>>(h1, nullptr, pool2_W, nullptr, pool2_b, m2,
                                  N_NODES);
  gather_max_pk<8><<<2048, 256, 0, stream>>>(
      (const uint4*)m2, ninfo, (const int*)bedges, (uint4*)agg2);
  node_gemm_mfma<HID_F, OUT_F, true, true, true, true, true>
      <<<ngrid, 256, 0, stream>>>(h1, agg2, self2_W, neigh2_W, bias2, h2,
                                  N_NODES);

  // ---- Edge scoring ----
  edge_score_bf16_kernel<<<4096, 256, 0, stream>>>((const uint4*)h2, src, dst,
                                                   pred_W, pred_b, out);
}